// Round 2
// baseline (198.604 us; speedup 1.0000x reference)
//
#include <hip/hip_runtime.h>

#define LAMBDA_COORD 5.0f
#define LAMBDA_NOOBJ 0.5f

// 802816 cells; preds 30 f32/cell (120 B), targets 25 f32/cell (100 B).
//
// v3: v1 (per-lane divergent loads) and v2 (fully coalesced LDS staging)
// both ran 68-70 us with identical FETCH_SIZE -> the bottleneck is the
// memory path's byte throughput (~2.6 TB/s composite), not the access
// pattern. So reduce DEMANDED bytes: only obj cells (t0==1, 30%) need the
// full 220 B; the other 70% need just p0, p5, t0 (12 B). Exec-masked
// lanes issue no addresses, so conditional loads shrink the cache-line
// footprint to ~83% (line-overlap limited; 120/100 B cells vs 64 B lines).
// If time scales with bytes -> ~56 us; if flat -> limit is per-request,
// which redirects the next step.

typedef float f4u __attribute__((ext_vector_type(4), aligned(4)));
typedef float f2u __attribute__((ext_vector_type(2), aligned(4)));

__global__ void zero_out_kernel(float* out, int n) {
    int i = blockIdx.x * blockDim.x + threadIdx.x;
    if (i < n) out[i] = 0.0f;
}

__global__ __launch_bounds__(256) void yolo_loss_kernel(
    const float* __restrict__ preds, const float* __restrict__ targets,
    float* __restrict__ out, int n_cells)
{
    __shared__ float s_part[4];
    const int tid = threadIdx.x;
    const int c = blockIdx.x * 256 + tid;

    float loss = 0.0f;
    if (c < n_cells) {
        const float* pbase = preds + (size_t)c * 30;
        const float* tbase = targets + (size_t)c * 25;

        // Always-needed 12 B: confidences p0,p5 and indicator t0.
        // Loading p0..p5 as x4+x2 touches exactly the same cache lines as
        // two scalar dwords at p0/p5 (window [0,24) of the cell), and gives
        // p1..p4 for free on the obj path.
        f4u P03 = *(const f4u*)(pbase + 0);   // p0..p3
        f2u P45 = *(const f2u*)(pbase + 4);   // p4,p5
        float t0 = tbase[0];

        float p0 = P03.x, p5c = P45.y;

        if (t0 == 1.0f) {
            // obj cell (30%): pull the rest of both cells.
            f4u P69 = *(const f4u*)(pbase + 6);    // p6..p9
            f4u C0 = *(const f4u*)(pbase + 10);    // p10..p13
            f4u C1 = *(const f4u*)(pbase + 14);
            f4u C2 = *(const f4u*)(pbase + 18);
            f4u C3 = *(const f4u*)(pbase + 22);
            f4u C4 = *(const f4u*)(pbase + 26);    // p26..p29
            f4u TB = *(const f4u*)(tbase + 1);     // t1..t4
            f4u U0 = *(const f4u*)(tbase + 5);     // t5..t8
            f4u U1 = *(const f4u*)(tbase + 9);
            f4u U2 = *(const f4u*)(tbase + 13);
            f4u U3 = *(const f4u*)(tbase + 17);
            f4u U4 = *(const f4u*)(tbase + 21);    // t21..t24

            // jnp.argmax picks first index on tie -> box1 only on strict greater.
            bool pick1 = p5c > p0;
            float b0 = pick1 ? p5c   : p0;
            float b1 = pick1 ? P69.x : P03.y;   // p6 : p1
            float b2 = pick1 ? P69.y : P03.z;   // p7 : p2
            float b3 = pick1 ? P69.z : P03.w;   // p8 : p3
            float b4 = pick1 ? P69.w : P45.x;   // p9 : p4

            float d1 = b1 - TB.x, d2 = b2 - TB.y, d3 = b3 - TB.z, d4 = b4 - TB.w;
            float box_loss = d1 * d1 + d2 * d2 + d3 * d3 + d4 * d4;
            float dpc = b0 - t0;
            float pc_loss = dpc * dpc;

            // classes p10..p29 vs t5..t24, strict sequential order (bit-match).
            float cl = 0.0f, d;
            d = C0.x - U0.x; cl += d * d;
            d = C0.y - U0.y; cl += d * d;
            d = C0.z - U0.z; cl += d * d;
            d = C0.w - U0.w; cl += d * d;
            d = C1.x - U1.x; cl += d * d;
            d = C1.y - U1.y; cl += d * d;
            d = C1.z - U1.z; cl += d * d;
            d = C1.w - U1.w; cl += d * d;
            d = C2.x - U2.x; cl += d * d;
            d = C2.y - U2.y; cl += d * d;
            d = C2.z - U2.z; cl += d * d;
            d = C2.w - U2.w; cl += d * d;
            d = C3.x - U3.x; cl += d * d;
            d = C3.y - U3.y; cl += d * d;
            d = C3.z - U3.z; cl += d * d;
            d = C3.w - U3.w; cl += d * d;
            d = C4.x - U4.x; cl += d * d;
            d = C4.y - U4.y; cl += d * d;
            d = C4.z - U4.z; cl += d * d;
            d = C4.w - U4.w; cl += d * d;

            loss = LAMBDA_COORD * box_loss + pc_loss + cl;
        } else {
            loss = LAMBDA_NOOBJ * (p0 * p0 + p5c * p5c);
        }
    }

    // wave (64-lane) shuffle reduction
    #pragma unroll
    for (int off = 32; off > 0; off >>= 1)
        loss += __shfl_down(loss, off, 64);

    const int wave = tid >> 6;
    if ((tid & 63) == 0) s_part[wave] = loss;
    __syncthreads();
    if (tid == 0) {
        float s = s_part[0] + s_part[1] + s_part[2] + s_part[3];
        atomicAdd(out, s);
    }
}

extern "C" void kernel_launch(void* const* d_in, const int* in_sizes, int n_in,
                              void* d_out, int out_size, void* d_ws, size_t ws_size,
                              hipStream_t stream) {
    const float* preds   = (const float*)d_in[0];
    const float* targets = (const float*)d_in[1];
    float* out = (float*)d_out;

    const int n_cells = in_sizes[0] / 30;   // 802816 (multiple of 256)

    // d_out is poisoned (0xAA) before every timed replay — zero it on-stream.
    zero_out_kernel<<<(out_size + 255) / 256, 256, 0, stream>>>(out, out_size);

    const int grid = (n_cells + 255) / 256; // 3136
    yolo_loss_kernel<<<grid, 256, 0, stream>>>(preds, targets, out, n_cells);
}

// Round 3
// 195.915 us; speedup vs baseline: 1.0137x; 1.0137x over previous
//
#include <hip/hip_runtime.h>

#define LAMBDA_COORD 5.0f
#define LAMBDA_NOOBJ 0.5f

// 802816 cells; preds 30 f32/cell (120 B), targets 25 f32/cell (100 B).
//
// v4: v1 (strided normal loads), v2 (wave-linear global_load_lds DMA) and
// v3 (exec-masked byte reduction) ALL run 68-70 us = 2.6 TB/s of demanded
// bytes, with HBM at only 16% and time invariant to FETCH_SIZE. Last
// untested canonical pattern: wave-linear float4 via NORMAL vmem loads
// into registers (the exact 6.3 TB/s copy-ubench shape), reg-staged into
// LDS with linear ds_write_b128, then per-cell compute from LDS. If this
// also lands at ~68 us, the wall is a shared L2-fill/service drain rate
// (~135 B/cycle/XCD) and we are at the machine's streaming-read roofline
// for this footprint.

typedef float f4 __attribute__((ext_vector_type(4)));          // 16-aligned
typedef float f4u __attribute__((ext_vector_type(4), aligned(4)));
typedef float f2u __attribute__((ext_vector_type(2), aligned(4)));

__global__ void zero_out_kernel(float* out, int n) {
    int i = blockIdx.x * blockDim.x + threadIdx.x;
    if (i < n) out[i] = 0.0f;
}

__global__ __launch_bounds__(256, 2) void yolo_loss_kernel(
    const float* __restrict__ preds, const float* __restrict__ targets,
    float* __restrict__ out, int n_cells)
{
    __shared__ f4 sp4[1920];   // 30720 B: block's 256 pred cells
    __shared__ f4 st4[1600];   // 25600 B: block's 256 target cells
    __shared__ float s_part[4];

    const int tid = threadIdx.x;
    const int block0 = blockIdx.x * 256;
    const bool full = (block0 + 256) <= n_cells;   // block-uniform

    float loss = 0.0f;

    if (full) {
        // slab bases: block0*120 B and block0*100 B, both multiples of 16
        // (block0 % 256 == 0) -> every f4 access below is 16 B aligned.
        const f4* pg = (const f4*)(preds + (size_t)block0 * 30);
        const f4* tg = (const f4*)(targets + (size_t)block0 * 25);

        // ---- wave-linear float4 loads into named registers ----
        // preds: 1920 f4 = 7*256 + 128
        f4 a0 = pg[tid];
        f4 a1 = pg[tid + 256];
        f4 a2 = pg[tid + 512];
        f4 a3 = pg[tid + 768];
        f4 a4 = pg[tid + 1024];
        f4 a5 = pg[tid + 1280];
        f4 a6 = pg[tid + 1536];
        f4 a7;
        if (tid < 128) a7 = pg[tid + 1792];
        // targets: 1600 f4 = 6*256 + 64
        f4 b0 = tg[tid];
        f4 b1 = tg[tid + 256];
        f4 b2 = tg[tid + 512];
        f4 b3 = tg[tid + 768];
        f4 b4 = tg[tid + 1024];
        f4 b5 = tg[tid + 1280];
        f4 b6;
        if (tid < 64) b6 = tg[tid + 1536];

        // ---- linear ds_write_b128 staging ----
        sp4[tid]        = a0;
        sp4[tid + 256]  = a1;
        sp4[tid + 512]  = a2;
        sp4[tid + 768]  = a3;
        sp4[tid + 1024] = a4;
        sp4[tid + 1280] = a5;
        sp4[tid + 1536] = a6;
        if (tid < 128) sp4[tid + 1792] = a7;
        st4[tid]        = b0;
        st4[tid + 256]  = b1;
        st4[tid + 512]  = b2;
        st4[tid + 768]  = b3;
        st4[tid + 1024] = b4;
        st4[tid + 1280] = b5;
        if (tid < 64) st4[tid + 1536] = b6;
        __syncthreads();

        const float* P = (const float*)sp4 + tid * 30;
        const float* T = (const float*)st4 + tid * 25;

        float q0 = P[0], q1 = P[1], q2 = P[2], q3 = P[3], q4 = P[4];
        float q5 = P[5], q6 = P[6], q7 = P[7], q8 = P[8], q9 = P[9];

        // jnp.argmax picks first index on tie -> box1 only on strict greater.
        bool pick1 = q5 > q0;
        float c0 = pick1 ? q5 : q0;
        float c1 = pick1 ? q6 : q1;
        float c2 = pick1 ? q7 : q2;
        float c3 = pick1 ? q8 : q3;
        float c4 = pick1 ? q9 : q4;

        float t0 = T[0];
        float d1 = c1 - T[1], d2 = c2 - T[2], d3 = c3 - T[3], d4 = c4 - T[4];
        float box_loss = d1 * d1 + d2 * d2 + d3 * d3 + d4 * d4;
        float dpc = c0 - t0;
        float pc_loss = dpc * dpc;

        float cl = 0.0f;
        #pragma unroll
        for (int k = 0; k < 20; ++k) {
            float d = P[10 + k] - T[5 + k];
            cl += d * d;
        }

        float obj_term = LAMBDA_COORD * box_loss + pc_loss + cl;
        float noobj_term = LAMBDA_NOOBJ * (q0 * q0 + q5 * q5);
        loss = (t0 == 1.0f) ? obj_term : noobj_term;
    } else {
        // ragged tail block (never taken for n_cells % 256 == 0): direct loads
        const int c = block0 + tid;
        if (c < n_cells) {
            const float* pbase = preds + (size_t)c * 30;
            const float* tbase = targets + (size_t)c * 25;
            const f4u* pp = (const f4u*)pbase;
            const f4u* tp = (const f4u*)tbase;

            f4u P0 = pp[0], P1 = pp[1], P2 = pp[2], P3 = pp[3];
            f4u P4 = pp[4], P5 = pp[5], P6 = pp[6];
            f2u P7 = *(const f2u*)(pbase + 28);
            f4u T0 = tp[0], T1 = tp[1], T2 = tp[2], T3 = tp[3];
            f4u T4 = tp[4], T5 = tp[5];
            float t24 = tbase[24];

            float p0 = P0.x, p5c = P1.y;
            bool pick1 = p5c > p0;
            float c0 = pick1 ? p5c  : p0;
            float c1 = pick1 ? P1.z : P0.y;
            float c2 = pick1 ? P1.w : P0.z;
            float c3 = pick1 ? P2.x : P0.w;
            float c4 = pick1 ? P2.y : P1.x;

            float t0 = T0.x;
            float d1 = c1 - T0.y, d2 = c2 - T0.z, d3 = c3 - T0.w, d4 = c4 - T1.x;
            float box_loss = d1 * d1 + d2 * d2 + d3 * d3 + d4 * d4;
            float dpc = c0 - t0;
            float pc_loss = dpc * dpc;

            float cl = 0.0f, d;
            d = P2.z - T1.y; cl += d * d;
            d = P2.w - T1.z; cl += d * d;
            d = P3.x - T1.w; cl += d * d;
            d = P3.y - T2.x; cl += d * d;
            d = P3.z - T2.y; cl += d * d;
            d = P3.w - T2.z; cl += d * d;
            d = P4.x - T2.w; cl += d * d;
            d = P4.y - T3.x; cl += d * d;
            d = P4.z - T3.y; cl += d * d;
            d = P4.w - T3.z; cl += d * d;
            d = P5.x - T3.w; cl += d * d;
            d = P5.y - T4.x; cl += d * d;
            d = P5.z - T4.y; cl += d * d;
            d = P5.w - T4.z; cl += d * d;
            d = P6.x - T4.w; cl += d * d;
            d = P6.y - T5.x; cl += d * d;
            d = P6.z - T5.y; cl += d * d;
            d = P6.w - T5.z; cl += d * d;
            d = P7.x - T5.w; cl += d * d;
            d = P7.y - t24;  cl += d * d;

            float obj_term = LAMBDA_COORD * box_loss + pc_loss + cl;
            float noobj_term = LAMBDA_NOOBJ * (p0 * p0 + p5c * p5c);
            loss = (t0 == 1.0f) ? obj_term : noobj_term;
        }
    }

    // wave (64-lane) shuffle reduction
    #pragma unroll
    for (int off = 32; off > 0; off >>= 1)
        loss += __shfl_down(loss, off, 64);

    const int wave = tid >> 6;
    if ((tid & 63) == 0) s_part[wave] = loss;
    __syncthreads();
    if (tid == 0) {
        float s = s_part[0] + s_part[1] + s_part[2] + s_part[3];
        atomicAdd(out, s);
    }
}

extern "C" void kernel_launch(void* const* d_in, const int* in_sizes, int n_in,
                              void* d_out, int out_size, void* d_ws, size_t ws_size,
                              hipStream_t stream) {
    const float* preds   = (const float*)d_in[0];
    const float* targets = (const float*)d_in[1];
    float* out = (float*)d_out;

    const int n_cells = in_sizes[0] / 30;   // 802816 (multiple of 256)

    // d_out is poisoned (0xAA) before every timed replay — zero it on-stream.
    zero_out_kernel<<<(out_size + 255) / 256, 256, 0, stream>>>(out, out_size);

    const int grid = (n_cells + 255) / 256; // 3136
    yolo_loss_kernel<<<grid, 256, 0, stream>>>(preds, targets, out, n_cells);
}